// Round 9
// baseline (704.955 us; speedup 1.0000x reference)
//
#include <hip/hip_runtime.h>
#include <math.h>

#define DIM 256
#define NQKV 768
#define STAT_BLOCKS 2048

typedef float  f32x4 __attribute__((ext_vector_type(4)));
typedef short  bs8   __attribute__((ext_vector_type(8)));

__device__ __forceinline__ ushort f2bf(float f) {
    unsigned int u = __float_as_uint(f);
    u += 0x7fffu + ((u >> 16) & 1u);
    return (ushort)(u >> 16);
}
__device__ __forceinline__ float bf2f(ushort u) {
    return __uint_as_float(((unsigned int)u) << 16);
}
// dot of 8 bf16 pairs packed in uint4 (fp32 accumulate)
__device__ __forceinline__ float dotu4(uint4 a, uint4 b) {
    float s;
    s  = bf2f((ushort)a.x) * bf2f((ushort)b.x) + bf2f((ushort)(a.x >> 16)) * bf2f((ushort)(b.x >> 16));
    s += bf2f((ushort)a.y) * bf2f((ushort)b.y) + bf2f((ushort)(a.y >> 16)) * bf2f((ushort)(b.y >> 16));
    s += bf2f((ushort)a.z) * bf2f((ushort)b.z) + bf2f((ushort)(a.z >> 16)) * bf2f((ushort)(b.z >> 16));
    s += bf2f((ushort)a.w) * bf2f((ushort)b.w) + bf2f((ushort)(a.w >> 16)) * bf2f((ushort)(b.w >> 16));
    return s;
}

#define MFMA16(c, a, b) \
    asm("s_nop 1\n\tv_mfma_f32_16x16x32_bf16 %0, %1, %2, %0" : "+v"(c) : "v"(a), "v"(b))

#define GLOAD_LDS16(g, l) __builtin_amdgcn_global_load_lds( \
    (const __attribute__((address_space(1))) unsigned int*)(g), \
    (__attribute__((address_space(3))) unsigned int*)(l), 16, 0, 0)

// ---------------------------------------------------------------------------
// K_A "prep": block-range dispatch of three independent jobs:
//   [0, nbConv)          : h (f32) -> h_bf (bf16), 8 elems/thread
//   [nbConv, nbConv+768) : build BmatT [768][256] bf16 combined weights
//   rest                 : per-dst degree count
// ---------------------------------------------------------------------------
__global__ __launch_bounds__(256) void prep(
    const float* __restrict__ h, ushort* __restrict__ h_bf, int total8, int nbConv,
    const float* __restrict__ attn_q, const float* __restrict__ attn_k,
    const float* __restrict__ W, ushort* __restrict__ bt,
    const int* __restrict__ dst, int* __restrict__ deg, int E)
{
    const int bx = blockIdx.x;
    if (bx < nbConv) {
        const int idx = bx * 256 + threadIdx.x;
        if (idx >= total8) return;
        const float4* hp = (const float4*)(h + (size_t)idx * 8);
        float4 a = hp[0], b = hp[1];
        uint4 o;
        o.x = (unsigned)f2bf(a.x) | ((unsigned)f2bf(a.y) << 16);
        o.y = (unsigned)f2bf(a.z) | ((unsigned)f2bf(a.w) << 16);
        o.z = (unsigned)f2bf(b.x) | ((unsigned)f2bf(b.y) << 16);
        o.w = (unsigned)f2bf(b.z) | ((unsigned)f2bf(b.w) << 16);
        *(uint4*)(h_bf + (size_t)idx * 8) = o;
    } else if (bx < nbConv + NQKV) {
        const int n = bx - nbConv;
        const int k = threadIdx.x;
        float val;
        if (n < 256)      val = attn_q[(size_t)k * 256 + n];
        else if (n < 512) val = attn_k[(size_t)k * 256 + (n - 256)];
        else              val = W[(size_t)(n - 512) * 256 + k];
        bt[(size_t)n * 256 + k] = f2bf(val);
    } else {
        const int e = (bx - nbConv - NQKV) * 256 + threadIdx.x;
        if (e < E) atomicAdd(&deg[dst[e]], 1);
    }
}

// ---------------------------------------------------------------------------
// K_B: single block shuffle-scan deg -> row_ptr; also writes cursor=row_ptr
// ---------------------------------------------------------------------------
__global__ __launch_bounds__(1024) void scan_rowptr(
    const int* __restrict__ deg, int* __restrict__ row_ptr,
    int* __restrict__ cursor, int N)
{
    const int tid  = threadIdx.x;
    const int lane = tid & 63;
    const int wv   = tid >> 6;

    if (tid == 0) { row_ptr[0] = 0; cursor[0] = 0; }

    __shared__ int woff[17];
    __shared__ int carryS;
    if (tid == 0) carryS = 0;
    __syncthreads();

    for (int base = 0; base < N; base += 4096) {
        int x[4], pre[4];
        int run = 0;
        #pragma unroll
        for (int j = 0; j < 4; ++j) {
            const int i = base + tid * 4 + j;
            const int v = (i < N) ? deg[i] : 0;
            pre[j] = run; x[j] = v; run += v;
        }
        int incl = run;
        #pragma unroll
        for (int off = 1; off < 64; off <<= 1) {
            int y = __shfl_up(incl, off);
            if (lane >= off) incl += y;
        }
        const int wex = incl - run;
        if (lane == 63) woff[wv] = incl;
        __syncthreads();
        if (wv == 0) {
            int wtot = (lane < 16) ? woff[lane] : 0;
            int winc = wtot;
            #pragma unroll
            for (int off = 1; off < 16; off <<= 1) {
                int y = __shfl_up(winc, off);
                if (lane >= off) winc += y;
            }
            if (lane < 16) woff[lane] = winc - wtot;
            if (lane == 15) woff[16] = winc;
        }
        __syncthreads();
        const int basev = carryS + woff[wv] + wex;
        #pragma unroll
        for (int j = 0; j < 4; ++j) {
            const int i = base + tid * 4 + j;
            if (i < N) {
                const int v = basev + pre[j] + x[j];
                row_ptr[i + 1] = v;
                cursor[i + 1]  = v;
            }
        }
        __syncthreads();
        if (tid == 0) carryS += woff[16];
        __syncthreads();
    }
}

// ---------------------------------------------------------------------------
// K_C "gemm_scatter": blocks [0,nbGemm) run the MFMA GEMM; the rest scatter
// edges into CSR order (independent work, overlapped on the same grid).
// GEMM: qkv[M][768] bf16 = h_bf[M][256] @ BmatT^T (+bias on v part).
// 128x128 tile, 4 waves, gload_lds staging with source-side chunk-XOR.
// ---------------------------------------------------------------------------
__global__ __launch_bounds__(256) void gemm_scatter(
    const ushort* __restrict__ h_bf, const ushort* __restrict__ bt,
    const float* __restrict__ bias, ushort* __restrict__ qkv, int M, int nbGemm,
    const int* __restrict__ src, const int* __restrict__ dst,
    int* __restrict__ cursor,
    int* __restrict__ srcc, int* __restrict__ dstc, int* __restrict__ orige, int E)
{
    __shared__ __align__(16) ushort As[128 * 32];   // 128 rows x 64B linear
    __shared__ __align__(16) ushort Bs[128 * 32];

    const int bx = blockIdx.x;
    if (bx >= nbGemm) {
        // ---------------- scatter branch ----------------
        const int e = (bx - nbGemm) * 256 + threadIdx.x;
        if (e < E) {
            const int d = dst[e];
            const int pos = atomicAdd(&cursor[d], 1);
            srcc[pos]  = src[e];
            dstc[pos]  = d;
            orige[pos] = e;
        }
        return;
    }

    // ---------------- GEMM branch ----------------
    const int bm = (bx / 6) * 128;
    const int bn = (bx % 6) * 128;
    const int t    = threadIdx.x;
    const int lane = t & 63;
    const int wid  = t >> 6;
    const int wm   = wid >> 1;
    const int wn   = wid & 1;
    const int fr   = lane & 15;

    const int srow0 = wid * 32 + (lane >> 2);
    const int srow1 = srow0 + 16;
    const int g0 = (lane & 3) ^ (srow0 & 3);
    const int g1 = (lane & 3) ^ (srow1 & 3);
    const int ga0 = min(bm + srow0, M - 1);
    const int ga1 = min(bm + srow1, M - 1);
    const int rchunk = ((lane >> 4) ^ (fr & 3)) * 8;

    f32x4 acc[4][4];
    #pragma unroll
    for (int i = 0; i < 4; ++i)
        #pragma unroll
        for (int j = 0; j < 4; ++j)
            acc[i][j] = (f32x4){0.f, 0.f, 0.f, 0.f};

    for (int k0 = 0; k0 < DIM; k0 += 32) {
        GLOAD_LDS16(h_bf + (size_t)ga0 * 256 + k0 + g0 * 8, As + (wid * 32) * 32);
        GLOAD_LDS16(h_bf + (size_t)ga1 * 256 + k0 + g1 * 8, As + (wid * 32 + 16) * 32);
        GLOAD_LDS16(bt + (size_t)(bn + srow0) * 256 + k0 + g0 * 8, Bs + (wid * 32) * 32);
        GLOAD_LDS16(bt + (size_t)(bn + srow1) * 256 + k0 + g1 * 8, Bs + (wid * 32 + 16) * 32);
        asm volatile("s_waitcnt vmcnt(0)" ::: "memory");
        __syncthreads();

        bs8 af[4], bf_[4];
        #pragma unroll
        for (int f = 0; f < 4; ++f) {
            af[f]  = *(const bs8*)(As + (wm * 64 + f * 16 + fr) * 32 + rchunk);
            bf_[f] = *(const bs8*)(Bs + (wn * 64 + f * 16 + fr) * 32 + rchunk);
        }
        #pragma unroll
        for (int fm = 0; fm < 4; ++fm)
            #pragma unroll
            for (int fn = 0; fn < 4; ++fn)
                MFMA16(acc[fm][fn], af[fm], bf_[fn]);

        __syncthreads();
    }

    asm volatile("s_nop 7\n\ts_nop 7\n\ts_nop 7" ::: );

    #pragma unroll
    for (int fm = 0; fm < 4; ++fm) {
        const int rowbase = bm + wm * 64 + fm * 16 + (lane >> 4) * 4;
        #pragma unroll
        for (int fn = 0; fn < 4; ++fn) {
            const int col = bn + wn * 64 + fn * 16 + fr;
            float bv = (col >= 512) ? bias[col - 512] : 0.f;
            #pragma unroll
            for (int r = 0; r < 4; ++r) {
                const int row = rowbase + r;
                if (row < M)
                    qkv[(size_t)row * NQKV + col] = f2bf(acc[fm][fn][r] + bv);
            }
        }
    }
}

// ---------------------------------------------------------------------------
// K_D: per-edge raw score in CSR order (half-wave per edge, 8 edges/iter)
// + per-block stat partials + LAST-BLOCK fused finalize -> coef.
// ---------------------------------------------------------------------------
__global__ __launch_bounds__(256) void edge_dot_csr(
    const ushort* __restrict__ qkv,
    const int* __restrict__ srcc, const int* __restrict__ dstc,
    float* __restrict__ a_rawc, double* __restrict__ partials,
    int* __restrict__ done, float* __restrict__ coef, int E)
{
    const int lane = threadIdx.x & 63;
    const int wid  = threadIdx.x >> 6;
    const int lq   = lane & 31;
    const int hh   = lane >> 5;
    const int w    = blockIdx.x * 4 + wid;
    const int nw   = gridDim.x * 4;
    const int chunk = (E + nw - 1) / nw;
    const int p0 = min(E, w * chunk);
    const int p1 = min(E, p0 + chunk);

    double lsum = 0.0, lsum2 = 0.0;
    int p = p0;

    for (; p + 8 <= p1; p += 8) {
        const int s0 = srcc[p     + hh], d0i = dstc[p     + hh];
        const int s1 = srcc[p + 2 + hh], d1i = dstc[p + 2 + hh];
        const int s2 = srcc[p + 4 + hh], d2i = dstc[p + 4 + hh];
        const int s3 = srcc[p + 6 + hh], d3i = dstc[p + 6 + hh];
        uint4 q0 = *(const uint4*)(qkv + (size_t)s0 * NQKV + lq * 8);
        uint4 q1 = *(const uint4*)(qkv + (size_t)s1 * NQKV + lq * 8);
        uint4 q2 = *(const uint4*)(qkv + (size_t)s2 * NQKV + lq * 8);
        uint4 q3 = *(const uint4*)(qkv + (size_t)s3 * NQKV + lq * 8);
        uint4 k0 = *(const uint4*)(qkv + (size_t)d0i * NQKV + 256 + lq * 8);
        uint4 k1 = *(const uint4*)(qkv + (size_t)d1i * NQKV + 256 + lq * 8);
        uint4 k2 = *(const uint4*)(qkv + (size_t)d2i * NQKV + 256 + lq * 8);
        uint4 k3 = *(const uint4*)(qkv + (size_t)d3i * NQKV + 256 + lq * 8);
        float d0 = dotu4(q0, k0);
        float d1 = dotu4(q1, k1);
        float d2 = dotu4(q2, k2);
        float d3 = dotu4(q3, k3);
        #pragma unroll
        for (int off = 16; off; off >>= 1) {
            d0 += __shfl_xor(d0, off);
            d1 += __shfl_xor(d1, off);
            d2 += __shfl_xor(d2, off);
            d3 += __shfl_xor(d3, off);
        }
        if (lq == 0) {
            a_rawc[p     + hh] = d0;
            a_rawc[p + 2 + hh] = d1;
            a_rawc[p + 4 + hh] = d2;
            a_rawc[p + 6 + hh] = d3;
            lsum  += (double)d0 + (double)d1 + (double)d2 + (double)d3;
            lsum2 += (double)d0 * d0 + (double)d1 * d1
                   + (double)d2 * d2 + (double)d3 * d3;
        }
    }
    for (; p + 2 <= p1; p += 2) {
        const int s0 = srcc[p + hh], d0i = dstc[p + hh];
        uint4 q0 = *(const uint4*)(qkv + (size_t)s0 * NQKV + lq * 8);
        uint4 k0 = *(const uint4*)(qkv + (size_t)d0i * NQKV + 256 + lq * 8);
        float d0 = dotu4(q0, k0);
        #pragma unroll
        for (int off = 16; off; off >>= 1) d0 += __shfl_xor(d0, off);
        if (lq == 0) {
            a_rawc[p + hh] = d0;
            lsum  += (double)d0;
            lsum2 += (double)d0 * d0;
        }
    }
    if (p < p1) {
        const int s0 = srcc[p], d0i = dstc[p];
        uint4 q0 = *(const uint4*)(qkv + (size_t)s0 * NQKV + lq * 8);
        uint4 k0 = *(const uint4*)(qkv + (size_t)d0i * NQKV + 256 + lq * 8);
        float d0 = dotu4(q0, k0);
        #pragma unroll
        for (int off = 16; off; off >>= 1) d0 += __shfl_xor(d0, off);
        if (lane == 0) {
            a_rawc[p] = d0;
            lsum  += (double)d0;
            lsum2 += (double)d0 * d0;
        }
    }

    lsum  += __shfl_xor(lsum, 32);
    lsum2 += __shfl_xor(lsum2, 32);

    __shared__ double bsum[4], bsum2[4];
    if (lane == 0) { bsum[wid] = lsum; bsum2[wid] = lsum2; }
    __syncthreads();
    if (threadIdx.x == 0) {
        partials[blockIdx.x]             = bsum[0] + bsum[1] + bsum[2] + bsum[3];
        partials[gridDim.x + blockIdx.x] = bsum2[0] + bsum2[1] + bsum2[2] + bsum2[3];
    }

    // ---- last-block fused finalize (done zeroed by graph memset each call) ----
    __threadfence();
    __shared__ int lastFlag;
    if (threadIdx.x == 0)
        lastFlag = (atomicAdd(done, 1) == (int)gridDim.x - 1);
    __syncthreads();
    if (!lastFlag) return;
    __threadfence();

    __shared__ double red[256];
    double s1 = 0.0, s2 = 0.0;
    for (int i = threadIdx.x; i < STAT_BLOCKS; i += 256) {
        s1 += partials[i];
        s2 += partials[STAT_BLOCKS + i];
    }
    red[threadIdx.x] = s1;
    __syncthreads();
    for (int off = 128; off; off >>= 1) {
        if (threadIdx.x < off) red[threadIdx.x] += red[threadIdx.x + off];
        __syncthreads();
    }
    const double tot1 = red[0];
    __syncthreads();
    red[threadIdx.x] = s2;
    __syncthreads();
    for (int off = 128; off; off >>= 1) {
        if (threadIdx.x < off) red[threadIdx.x] += red[threadIdx.x + off];
        __syncthreads();
    }
    if (threadIdx.x == 0) {
        const double mean = tot1 / (double)E;
        const double var  = red[0] / (double)E - mean * mean;
        coef[0] = (float)mean;
        coef[1] = (float)(1.0 / (sqrt(var) * 0.5));   // /std /TEMPERATURE
    }
}

// ---------------------------------------------------------------------------
// K_E: fused per-node softmax + aggregation, wave-per-node, 8-deep gather.
// ---------------------------------------------------------------------------
__global__ __launch_bounds__(256) void agg_fused(
    const ushort* __restrict__ qkv, const float* __restrict__ a_rawc,
    const int* __restrict__ srcc, const int* __restrict__ orige,
    const int* __restrict__ row_ptr, const float* __restrict__ coef,
    float* __restrict__ out, float* __restrict__ a_out, int N)
{
    const int lane = threadIdx.x & 63;
    const int wv   = threadIdx.x >> 6;
    const int node = blockIdx.x * 4 + wv;
    if (node >= N) return;          // safe: no block-wide barriers below

    const int s   = row_ptr[node];
    const int deg = row_ptr[node + 1] - s;
    const float mean = coef[0];
    const float mul  = coef[1];

    __shared__ float wbuf_s[4][128];
    __shared__ int   sbuf_s[4][128];
    float* wbuf = wbuf_s[wv];
    int*   sbuf = sbuf_s[wv];

    // ---- phase 1: softmax denominator ----
    float lsum = 0.f;
    for (int j = lane; j < deg; j += 64)
        lsum += __expf((a_rawc[s + j] - mean) * mul);
    #pragma unroll
    for (int off = 32; off; off >>= 1) lsum += __shfl_xor(lsum, off);
    const float rcp = 1.0f / lsum;

    // ---- phase 2: weights to LDS + a_out, then weighted v-gather ----
    float4 acc = make_float4(0.f, 0.f, 0.f, 0.f);
    for (int b0 = 0; b0 < deg; b0 += 128) {
        const int bc = min(128, deg - b0);
        for (int j = lane; j < bc; j += 64) {
            const float wgt = __expf((a_rawc[s + b0 + j] - mean) * mul) * rcp;
            wbuf[j] = wgt;
            sbuf[j] = srcc[s + b0 + j];
            a_out[orige[s + b0 + j]] = wgt;
        }
        asm volatile("s_waitcnt lgkmcnt(0)" ::: "memory");
        __builtin_amdgcn_sched_barrier(0);

        int j = 0;
        for (; j + 8 <= bc; j += 8) {
            float wv8[8]; int si8[8];
            #pragma unroll
            for (int u = 0; u < 8; ++u) { wv8[u] = wbuf[j + u]; si8[u] = sbuf[j + u]; }
            ushort4 vv[8];
            #pragma unroll
            for (int u = 0; u < 8; ++u)
                vv[u] = *(const ushort4*)(qkv + (size_t)si8[u] * NQKV + 512 + lane * 4);
            #pragma unroll
            for (int u = 0; u < 8; ++u) {
                acc.x += wv8[u] * bf2f(vv[u].x);
                acc.y += wv8[u] * bf2f(vv[u].y);
                acc.z += wv8[u] * bf2f(vv[u].z);
                acc.w += wv8[u] * bf2f(vv[u].w);
            }
        }
        for (; j < bc; ++j) {
            const float w0 = wbuf[j];
            const int   s0 = sbuf[j];
            ushort4 v0 = *(const ushort4*)(qkv + (size_t)s0 * NQKV + 512 + lane * 4);
            acc.x += w0 * bf2f(v0.x);
            acc.y += w0 * bf2f(v0.y);
            acc.z += w0 * bf2f(v0.z);
            acc.w += w0 * bf2f(v0.w);
        }
    }

    *(float4*)&out[(size_t)node * DIM + lane * 4] = acc;
}

// ---------------------------------------------------------------------------
extern "C" void kernel_launch(void* const* d_in, const int* in_sizes, int n_in,
                              void* d_out, int out_size, void* d_ws, size_t ws_size,
                              hipStream_t stream)
{
    const float* h      = (const float*)d_in[0];
    const int*   src    = (const int*)d_in[1];
    const int*   dst    = (const int*)d_in[2];
    const float* attn_q = (const float*)d_in[3];
    const float* attn_k = (const float*)d_in[4];
    const float* W      = (const float*)d_in[5];
    const float* bias   = (const float*)d_in[6];

    const int N = in_sizes[0] / DIM;
    const int E = in_sizes[1];

    float* out   = (float*)d_out;
    float* a_out = out + (size_t)N * DIM;

    char* ws = (char*)d_ws;
    ushort* h_bf  = (ushort*)ws; ws += (size_t)N * DIM * 2;      // 25.6 MB
    ushort* qkv   = (ushort*)ws; ws += (size_t)N * NQKV * 2;     // 76.8 MB
    ushort* bt    = (ushort*)ws; ws += (size_t)NQKV * DIM * 2;   // 0.4 MB
    float* a_rawc = (float*)ws;  ws += (size_t)E * 4;            // 3.2 MB
    int* srcc     = (int*)ws;    ws += (size_t)E * 4;            // 3.2 MB
    int* dstc     = (int*)ws;    ws += (size_t)E * 4;            // 3.2 MB
    int* orige    = (int*)ws;    ws += (size_t)E * 4;            // 3.2 MB
    int* deg      = (int*)ws;    ws += (size_t)N * 4;
    int* done     = (int*)ws;    ws += 64;                       // adjacent to deg
    int* cursor   = (int*)ws;    ws += (size_t)(N + 1) * 4;
    double* partials = (double*)ws; ws += (size_t)STAT_BLOCKS * 2 * 8;
    float* coef   = (float*)ws;  ws += 64;
    int* row_ptr  = (int*)ws;    ws += (size_t)(N + 1) * 4;

    // zero deg + done in one memset (they are contiguous)
    hipMemsetAsync(deg, 0, (size_t)N * 4 + 64, stream);

    const int total8 = N * DIM / 8;
    const int nbConv = (total8 + 255) / 256;
    const int nbDeg  = (E + 255) / 256;
    prep<<<nbConv + NQKV + nbDeg, 256, 0, stream>>>(
        h, h_bf, total8, nbConv, attn_q, attn_k, W, bt, dst, deg, E);

    scan_rowptr<<<1, 1024, 0, stream>>>(deg, row_ptr, cursor, N);

    const int nbGemm = ((N + 127) / 128) * 6;
    gemm_scatter<<<nbGemm + nbDeg, 256, 0, stream>>>(
        h_bf, bt, bias, qkv, N, nbGemm, src, dst, cursor, srcc, dstc, orige, E);

    edge_dot_csr<<<STAT_BLOCKS, 256, 0, stream>>>(
        qkv, srcc, dstc, a_rawc, partials, done, coef, E);

    agg_fused<<<(N + 3) / 4, 256, 0, stream>>>(
        qkv, a_rawc, srcc, orige, row_ptr, coef, out, a_out, N);
}

// Round 10
// 438.725 us; speedup vs baseline: 1.6068x; 1.6068x over previous
//
#include <hip/hip_runtime.h>
#include <math.h>

#define DIM 256
#define NQKV 768
#define STAT_BLOCKS 2048

typedef float  f32x4 __attribute__((ext_vector_type(4)));
typedef short  bs8   __attribute__((ext_vector_type(8)));

__device__ __forceinline__ ushort f2bf(float f) {
    unsigned int u = __float_as_uint(f);
    u += 0x7fffu + ((u >> 16) & 1u);
    return (ushort)(u >> 16);
}
__device__ __forceinline__ float bf2f(ushort u) {
    return __uint_as_float(((unsigned int)u) << 16);
}
// dot of 8 bf16 pairs packed in uint4 (fp32 accumulate)
__device__ __forceinline__ float dotu4(uint4 a, uint4 b) {
    float s;
    s  = bf2f((ushort)a.x) * bf2f((ushort)b.x) + bf2f((ushort)(a.x >> 16)) * bf2f((ushort)(b.x >> 16));
    s += bf2f((ushort)a.y) * bf2f((ushort)b.y) + bf2f((ushort)(a.y >> 16)) * bf2f((ushort)(b.y >> 16));
    s += bf2f((ushort)a.z) * bf2f((ushort)b.z) + bf2f((ushort)(a.z >> 16)) * bf2f((ushort)(b.z >> 16));
    s += bf2f((ushort)a.w) * bf2f((ushort)b.w) + bf2f((ushort)(a.w >> 16)) * bf2f((ushort)(b.w >> 16));
    return s;
}

#define MFMA16(c, a, b) \
    asm("s_nop 1\n\tv_mfma_f32_16x16x32_bf16 %0, %1, %2, %0" : "+v"(c) : "v"(a), "v"(b))

#define GLOAD_LDS16(g, l) __builtin_amdgcn_global_load_lds( \
    (const __attribute__((address_space(1))) unsigned int*)(g), \
    (__attribute__((address_space(3))) unsigned int*)(l), 16, 0, 0)

// ---------------------------------------------------------------------------
// K_A "prep": block-range dispatch of three independent jobs:
//   [0, nbConv)          : h (f32) -> h_bf (bf16), 8 elems/thread
//   [nbConv, nbConv+768) : build BmatT [768][256] bf16 combined weights
//   rest                 : per-dst degree count
// ---------------------------------------------------------------------------
__global__ __launch_bounds__(256) void prep(
    const float* __restrict__ h, ushort* __restrict__ h_bf, int total8, int nbConv,
    const float* __restrict__ attn_q, const float* __restrict__ attn_k,
    const float* __restrict__ W, ushort* __restrict__ bt,
    const int* __restrict__ dst, int* __restrict__ deg, int E)
{
    const int bx = blockIdx.x;
    if (bx < nbConv) {
        const int idx = bx * 256 + threadIdx.x;
        if (idx >= total8) return;
        const float4* hp = (const float4*)(h + (size_t)idx * 8);
        float4 a = hp[0], b = hp[1];
        uint4 o;
        o.x = (unsigned)f2bf(a.x) | ((unsigned)f2bf(a.y) << 16);
        o.y = (unsigned)f2bf(a.z) | ((unsigned)f2bf(a.w) << 16);
        o.z = (unsigned)f2bf(b.x) | ((unsigned)f2bf(b.y) << 16);
        o.w = (unsigned)f2bf(b.z) | ((unsigned)f2bf(b.w) << 16);
        *(uint4*)(h_bf + (size_t)idx * 8) = o;
    } else if (bx < nbConv + NQKV) {
        const int n = bx - nbConv;
        const int k = threadIdx.x;
        float val;
        if (n < 256)      val = attn_q[(size_t)k * 256 + n];
        else if (n < 512) val = attn_k[(size_t)k * 256 + (n - 256)];
        else              val = W[(size_t)(n - 512) * 256 + k];
        bt[(size_t)n * 256 + k] = f2bf(val);
    } else {
        const int e = (bx - nbConv - NQKV) * 256 + threadIdx.x;
        if (e < E) atomicAdd(&deg[dst[e]], 1);
    }
}

// ---------------------------------------------------------------------------
// K_B: single block shuffle-scan deg -> row_ptr; also writes cursor=row_ptr
// ---------------------------------------------------------------------------
__global__ __launch_bounds__(1024) void scan_rowptr(
    const int* __restrict__ deg, int* __restrict__ row_ptr,
    int* __restrict__ cursor, int N)
{
    const int tid  = threadIdx.x;
    const int lane = tid & 63;
    const int wv   = tid >> 6;

    if (tid == 0) { row_ptr[0] = 0; cursor[0] = 0; }

    __shared__ int woff[17];
    __shared__ int carryS;
    if (tid == 0) carryS = 0;
    __syncthreads();

    for (int base = 0; base < N; base += 4096) {
        int x[4], pre[4];
        int run = 0;
        #pragma unroll
        for (int j = 0; j < 4; ++j) {
            const int i = base + tid * 4 + j;
            const int v = (i < N) ? deg[i] : 0;
            pre[j] = run; x[j] = v; run += v;
        }
        int incl = run;
        #pragma unroll
        for (int off = 1; off < 64; off <<= 1) {
            int y = __shfl_up(incl, off);
            if (lane >= off) incl += y;
        }
        const int wex = incl - run;
        if (lane == 63) woff[wv] = incl;
        __syncthreads();
        if (wv == 0) {
            int wtot = (lane < 16) ? woff[lane] : 0;
            int winc = wtot;
            #pragma unroll
            for (int off = 1; off < 16; off <<= 1) {
                int y = __shfl_up(winc, off);
                if (lane >= off) winc += y;
            }
            if (lane < 16) woff[lane] = winc - wtot;
            if (lane == 15) woff[16] = winc;
        }
        __syncthreads();
        const int basev = carryS + woff[wv] + wex;
        #pragma unroll
        for (int j = 0; j < 4; ++j) {
            const int i = base + tid * 4 + j;
            if (i < N) {
                const int v = basev + pre[j] + x[j];
                row_ptr[i + 1] = v;
                cursor[i + 1]  = v;
            }
        }
        __syncthreads();
        if (tid == 0) carryS += woff[16];
        __syncthreads();
    }
}

// ---------------------------------------------------------------------------
// K_C "gemm_scatter": blocks [0,nbGemm) run the MFMA GEMM; the rest scatter
// edges into CSR order (independent work, overlapped on the same grid).
// ---------------------------------------------------------------------------
__global__ __launch_bounds__(256) void gemm_scatter(
    const ushort* __restrict__ h_bf, const ushort* __restrict__ bt,
    const float* __restrict__ bias, ushort* __restrict__ qkv, int M, int nbGemm,
    const int* __restrict__ src, const int* __restrict__ dst,
    int* __restrict__ cursor, int4* __restrict__ edata, int E)
{
    __shared__ __align__(16) ushort As[128 * 32];   // 128 rows x 64B linear
    __shared__ __align__(16) ushort Bs[128 * 32];

    const int bx = blockIdx.x;
    if (bx >= nbGemm) {
        // ---------------- scatter branch (cursor prefilled = row_ptr) ------
        const int e = (bx - nbGemm) * 256 + threadIdx.x;
        if (e < E) {
            const int d = dst[e];
            const int pos = atomicAdd(&cursor[d], 1);
            edata[pos] = make_int4(src[e], d, e, 0);
        }
        return;
    }

    // ---------------- GEMM branch ----------------
    const int bm = (bx / 6) * 128;
    const int bn = (bx % 6) * 128;
    const int t    = threadIdx.x;
    const int lane = t & 63;
    const int wid  = t >> 6;
    const int wm   = wid >> 1;
    const int wn   = wid & 1;
    const int fr   = lane & 15;

    const int srow0 = wid * 32 + (lane >> 2);
    const int srow1 = srow0 + 16;
    const int g0 = (lane & 3) ^ (srow0 & 3);
    const int g1 = (lane & 3) ^ (srow1 & 3);
    const int ga0 = min(bm + srow0, M - 1);
    const int ga1 = min(bm + srow1, M - 1);
    const int rchunk = ((lane >> 4) ^ (fr & 3)) * 8;

    f32x4 acc[4][4];
    #pragma unroll
    for (int i = 0; i < 4; ++i)
        #pragma unroll
        for (int j = 0; j < 4; ++j)
            acc[i][j] = (f32x4){0.f, 0.f, 0.f, 0.f};

    for (int k0 = 0; k0 < DIM; k0 += 32) {
        GLOAD_LDS16(h_bf + (size_t)ga0 * 256 + k0 + g0 * 8, As + (wid * 32) * 32);
        GLOAD_LDS16(h_bf + (size_t)ga1 * 256 + k0 + g1 * 8, As + (wid * 32 + 16) * 32);
        GLOAD_LDS16(bt + (size_t)(bn + srow0) * 256 + k0 + g0 * 8, Bs + (wid * 32) * 32);
        GLOAD_LDS16(bt + (size_t)(bn + srow1) * 256 + k0 + g1 * 8, Bs + (wid * 32 + 16) * 32);
        asm volatile("s_waitcnt vmcnt(0)" ::: "memory");
        __syncthreads();

        bs8 af[4], bf_[4];
        #pragma unroll
        for (int f = 0; f < 4; ++f) {
            af[f]  = *(const bs8*)(As + (wm * 64 + f * 16 + fr) * 32 + rchunk);
            bf_[f] = *(const bs8*)(Bs + (wn * 64 + f * 16 + fr) * 32 + rchunk);
        }
        #pragma unroll
        for (int fm = 0; fm < 4; ++fm)
            #pragma unroll
            for (int fn = 0; fn < 4; ++fn)
                MFMA16(acc[fm][fn], af[fm], bf_[fn]);

        __syncthreads();
    }

    asm volatile("s_nop 7\n\ts_nop 7\n\ts_nop 7" ::: );

    #pragma unroll
    for (int fm = 0; fm < 4; ++fm) {
        const int rowbase = bm + wm * 64 + fm * 16 + (lane >> 4) * 4;
        #pragma unroll
        for (int fn = 0; fn < 4; ++fn) {
            const int col = bn + wn * 64 + fn * 16 + fr;
            float bv = (col >= 512) ? bias[col - 512] : 0.f;
            #pragma unroll
            for (int r = 0; r < 4; ++r) {
                const int row = rowbase + r;
                if (row < M)
                    qkv[(size_t)row * NQKV + col] = f2bf(acc[fm][fn][r] + bv);
            }
        }
    }
}

// ---------------------------------------------------------------------------
// K_D: per-edge raw score in CSR order (half-wave per edge, 8 edges/iter).
// R8-proven structure: int4 edata loads, per-block partials, NO fences.
// ---------------------------------------------------------------------------
__global__ __launch_bounds__(256) void edge_dot_csr(
    const ushort* __restrict__ qkv, const int4* __restrict__ edata,
    float* __restrict__ a_rawc, double* __restrict__ partials, int E)
{
    const int lane = threadIdx.x & 63;
    const int wid  = threadIdx.x >> 6;
    const int lq   = lane & 31;
    const int hh   = lane >> 5;
    const int w    = blockIdx.x * 4 + wid;
    const int nw   = gridDim.x * 4;
    const int chunk = (E + nw - 1) / nw;
    const int p0 = min(E, w * chunk);
    const int p1 = min(E, p0 + chunk);

    double lsum = 0.0, lsum2 = 0.0;
    int p = p0;

    for (; p + 8 <= p1; p += 8) {
        const int4 ed0 = edata[p     + hh];
        const int4 ed1 = edata[p + 2 + hh];
        const int4 ed2 = edata[p + 4 + hh];
        const int4 ed3 = edata[p + 6 + hh];
        uint4 q0 = *(const uint4*)(qkv + (size_t)ed0.x * NQKV + lq * 8);
        uint4 q1 = *(const uint4*)(qkv + (size_t)ed1.x * NQKV + lq * 8);
        uint4 q2 = *(const uint4*)(qkv + (size_t)ed2.x * NQKV + lq * 8);
        uint4 q3 = *(const uint4*)(qkv + (size_t)ed3.x * NQKV + lq * 8);
        uint4 k0 = *(const uint4*)(qkv + (size_t)ed0.y * NQKV + 256 + lq * 8);
        uint4 k1 = *(const uint4*)(qkv + (size_t)ed1.y * NQKV + 256 + lq * 8);
        uint4 k2 = *(const uint4*)(qkv + (size_t)ed2.y * NQKV + 256 + lq * 8);
        uint4 k3 = *(const uint4*)(qkv + (size_t)ed3.y * NQKV + 256 + lq * 8);
        float d0 = dotu4(q0, k0);
        float d1 = dotu4(q1, k1);
        float d2 = dotu4(q2, k2);
        float d3 = dotu4(q3, k3);
        #pragma unroll
        for (int off = 16; off; off >>= 1) {
            d0 += __shfl_xor(d0, off);
            d1 += __shfl_xor(d1, off);
            d2 += __shfl_xor(d2, off);
            d3 += __shfl_xor(d3, off);
        }
        if (lq == 0) {
            a_rawc[p     + hh] = d0;
            a_rawc[p + 2 + hh] = d1;
            a_rawc[p + 4 + hh] = d2;
            a_rawc[p + 6 + hh] = d3;
            lsum  += (double)d0 + (double)d1 + (double)d2 + (double)d3;
            lsum2 += (double)d0 * d0 + (double)d1 * d1
                   + (double)d2 * d2 + (double)d3 * d3;
        }
    }
    for (; p + 2 <= p1; p += 2) {
        const int4 ed0 = edata[p + hh];
        uint4 q0 = *(const uint4*)(qkv + (size_t)ed0.x * NQKV + lq * 8);
        uint4 k0 = *(const uint4*)(qkv + (size_t)ed0.y * NQKV + 256 + lq * 8);
        float d0 = dotu4(q0, k0);
        #pragma unroll
        for (int off = 16; off; off >>= 1) d0 += __shfl_xor(d0, off);
        if (lq == 0) {
            a_rawc[p + hh] = d0;
            lsum  += (double)d0;
            lsum2 += (double)d0 * d0;
        }
    }
    if (p < p1) {   // single tail edge
        const int4 ed0 = edata[p];
        uint4 q0 = *(const uint4*)(qkv + (size_t)ed0.x * NQKV + lq * 8);
        uint4 k0 = *(const uint4*)(qkv + (size_t)ed0.y * NQKV + 256 + lq * 8);
        float d0 = dotu4(q0, k0);
        #pragma unroll
        for (int off = 16; off; off >>= 1) d0 += __shfl_xor(d0, off);
        if (lane == 0) {
            a_rawc[p] = d0;
            lsum  += (double)d0;
            lsum2 += (double)d0 * d0;
        }
    }

    lsum  += __shfl_xor(lsum, 32);
    lsum2 += __shfl_xor(lsum2, 32);

    __shared__ double bsum[4], bsum2[4];
    if (lane == 0) { bsum[wid] = lsum; bsum2[wid] = lsum2; }
    __syncthreads();
    if (threadIdx.x == 0) {
        partials[blockIdx.x]             = bsum[0] + bsum[1] + bsum[2] + bsum[3];
        partials[gridDim.x + blockIdx.x] = bsum2[0] + bsum2[1] + bsum2[2] + bsum2[3];
    }
}

// ---------------------------------------------------------------------------
// K_E: reduce stat partials -> coef {mean, 1/(std*T)}  (separate tiny kernel;
// fusing this via threadfence/done cost 300us in R9 — never again)
// ---------------------------------------------------------------------------
__global__ __launch_bounds__(256) void finalize_coef(
    const double* __restrict__ partials, float* __restrict__ coef, int E)
{
    __shared__ double red[256];
    const int tid = threadIdx.x;
    double s1 = 0.0, s2 = 0.0;
    for (int i = tid; i < STAT_BLOCKS; i += 256) {
        s1 += partials[i];
        s2 += partials[STAT_BLOCKS + i];
    }
    red[tid] = s1;
    __syncthreads();
    for (int off = 128; off; off >>= 1) {
        if (tid < off) red[tid] += red[tid + off];
        __syncthreads();
    }
    const double tot1 = red[0];
    __syncthreads();
    red[tid] = s2;
    __syncthreads();
    for (int off = 128; off; off >>= 1) {
        if (tid < off) red[tid] += red[tid + off];
        __syncthreads();
    }
    if (tid == 0) {
        const double mean = tot1 / (double)E;
        const double var  = red[0] / (double)E - mean * mean;
        coef[0] = (float)mean;
        coef[1] = (float)(1.0 / (sqrt(var) * 0.5));   // /std /TEMPERATURE
    }
}

// ---------------------------------------------------------------------------
// K_F: fused per-node softmax + aggregation, wave-per-node, 8-deep gather.
// ---------------------------------------------------------------------------
__global__ __launch_bounds__(256) void agg_fused(
    const ushort* __restrict__ qkv, const float* __restrict__ a_rawc,
    const int4* __restrict__ edata, const int* __restrict__ row_ptr,
    const float* __restrict__ coef,
    float* __restrict__ out, float* __restrict__ a_out, int N)
{
    const int lane = threadIdx.x & 63;
    const int wv   = threadIdx.x >> 6;
    const int node = blockIdx.x * 4 + wv;
    if (node >= N) return;          // safe: no block-wide barriers below

    const int s   = row_ptr[node];
    const int deg = row_ptr[node + 1] - s;
    const float mean = coef[0];
    const float mul  = coef[1];

    __shared__ float wbuf_s[4][128];
    __shared__ int   sbuf_s[4][128];
    float* wbuf = wbuf_s[wv];
    int*   sbuf = sbuf_s[wv];

    // ---- phase 1: softmax denominator ----
    float lsum = 0.f;
    for (int j = lane; j < deg; j += 64)
        lsum += __expf((a_rawc[s + j] - mean) * mul);
    #pragma unroll
    for (int off = 32; off; off >>= 1) lsum += __shfl_xor(lsum, off);
    const float rcp = 1.0f / lsum;

    // ---- phase 2: weights to LDS + a_out, then weighted v-gather ----
    float4 acc = make_float4(0.f, 0.f, 0.f, 0.f);
    for (int b0 = 0; b0 < deg; b0 += 128) {
        const int bc = min(128, deg - b0);
        for (int j = lane; j < bc; j += 64) {
            const int4 ed = edata[s + b0 + j];
            const float wgt = __expf((a_rawc[s + b0 + j] - mean) * mul) * rcp;
            wbuf[j] = wgt;
            sbuf[j] = ed.x;
            a_out[ed.z] = wgt;
        }
        asm volatile("s_waitcnt lgkmcnt(0)" ::: "memory");
        __builtin_amdgcn_sched_barrier(0);

        int j = 0;
        for (; j + 8 <= bc; j += 8) {
            float wv8[8]; int si8[8];
            #pragma unroll
            for (int u = 0; u < 8; ++u) { wv8[u] = wbuf[j + u]; si8[u] = sbuf[j + u]; }
            ushort4 vv[8];
            #pragma unroll
            for (int u = 0; u < 8; ++u)
                vv[u] = *(const ushort4*)(qkv + (size_t)si8[u] * NQKV + 512 + lane * 4);
            #pragma unroll
            for (int u = 0; u < 8; ++u) {
                acc.x += wv8[u] * bf2f(vv[u].x);
                acc.y += wv8[u] * bf2f(vv[u].y);
                acc.z += wv8[u] * bf2f(vv[u].z);
                acc.w += wv8[u] * bf2f(vv[u].w);
            }
        }
        for (; j < bc; ++j) {
            const float w0 = wbuf[j];
            const int   s0 = sbuf[j];
            ushort4 v0 = *(const ushort4*)(qkv + (size_t)s0 * NQKV + 512 + lane * 4);
            acc.x += w0 * bf2f(v0.x);
            acc.y += w0 * bf2f(v0.y);
            acc.z += w0 * bf2f(v0.z);
            acc.w += w0 * bf2f(v0.w);
        }
    }

    *(float4*)&out[(size_t)node * DIM + lane * 4] = acc;
}

// ---------------------------------------------------------------------------
extern "C" void kernel_launch(void* const* d_in, const int* in_sizes, int n_in,
                              void* d_out, int out_size, void* d_ws, size_t ws_size,
                              hipStream_t stream)
{
    const float* h      = (const float*)d_in[0];
    const int*   src    = (const int*)d_in[1];
    const int*   dst    = (const int*)d_in[2];
    const float* attn_q = (const float*)d_in[3];
    const float* attn_k = (const float*)d_in[4];
    const float* W      = (const float*)d_in[5];
    const float* bias   = (const float*)d_in[6];

    const int N = in_sizes[0] / DIM;
    const int E = in_sizes[1];

    float* out   = (float*)d_out;
    float* a_out = out + (size_t)N * DIM;

    char* ws = (char*)d_ws;
    ushort* h_bf  = (ushort*)ws; ws += (size_t)N * DIM * 2;      // 25.6 MB
    ushort* qkv   = (ushort*)ws; ws += (size_t)N * NQKV * 2;     // 76.8 MB
    ushort* bt    = (ushort*)ws; ws += (size_t)NQKV * DIM * 2;   // 0.4 MB
    float* a_rawc = (float*)ws;  ws += (size_t)E * 4;            // 3.2 MB
    int4* edata   = (int4*)ws;   ws += (size_t)E * 16;           // 12.8 MB
    int* deg      = (int*)ws;    ws += (size_t)N * 4;
    int* cursor   = (int*)ws;    ws += (size_t)(N + 1) * 4;
    double* partials = (double*)ws; ws += (size_t)STAT_BLOCKS * 2 * 8;
    float* coef   = (float*)ws;  ws += 64;
    int* row_ptr  = (int*)ws;    ws += (size_t)(N + 1) * 4;

    hipMemsetAsync(deg, 0, (size_t)N * 4, stream);

    const int total8 = N * DIM / 8;
    const int nbConv = (total8 + 255) / 256;
    const int nbDeg  = (E + 255) / 256;
    prep<<<nbConv + NQKV + nbDeg, 256, 0, stream>>>(
        h, h_bf, total8, nbConv, attn_q, attn_k, W, bt, dst, deg, E);

    scan_rowptr<<<1, 1024, 0, stream>>>(deg, row_ptr, cursor, N);

    const int nbGemm = ((N + 127) / 128) * 6;
    gemm_scatter<<<nbGemm + nbDeg, 256, 0, stream>>>(
        h_bf, bt, bias, qkv, N, nbGemm, src, dst, cursor, edata, E);

    edge_dot_csr<<<STAT_BLOCKS, 256, 0, stream>>>(
        qkv, edata, a_rawc, partials, E);

    finalize_coef<<<1, 256, 0, stream>>>(partials, coef, E);

    agg_fused<<<(N + 3) / 4, 256, 0, stream>>>(
        qkv, a_rawc, edata, row_ptr, coef, out, a_out, N);
}